// Round 4
// baseline (901.524 us; speedup 1.0000x reference)
//
#include <hip/hip_runtime.h>
#include <stdint.h>

#define NB 8
#define NP 4096
#define NS 1024
#define NK 64
#define ND 64
#define NH 64
#define NCO 128

#define PPT2 16            // producer: 4 waves x 256 threads x 16 points

// padded K strides (in halves) for conflict-free b128 LDS access
#define K1P 104            // layer1 K: 64 x-ch + 3 xyz + zeros to 96, padded to 104
#define K2P 72             // layer2/3 K: 64, padded to 72

// workspace layout (bytes)
#define WS_WIDX 0          // int[NB*NS] per-step winner index tokens (32 KB)
#define WS_WT   32768      // _Float16 weights (20480 halves = 40 KB)

typedef _Float16 half8v __attribute__((ext_vector_type(8)));
typedef _Float16 half4v __attribute__((ext_vector_type(4)));
typedef _Float16 half2v __attribute__((ext_vector_type(2)));
typedef float    floatx4 __attribute__((ext_vector_type(4)));
typedef float    floatx2 __attribute__((ext_vector_type(2)));

// DPP move helper (ctrl must be compile-time constant)
template <int CTRL>
__device__ __forceinline__ float dpp_mov_f32(float x) {
    return __int_as_float(__builtin_amdgcn_update_dpp(
        0, __float_as_int(x), CTRL, 0xf, 0xf, true));
}

// select point k (0..15) from 8 packed float2 regs; all indices literal ->
// pure cndmask tree, no scratch. arr[j] holds points {2j (.x), 2j+1 (.y)}.
#define SEL16(arr, k, out) do {                                   \
    floatx2 _u0 = ((k) & 2) ? arr[1] : arr[0];                    \
    floatx2 _u1 = ((k) & 2) ? arr[3] : arr[2];                    \
    floatx2 _u2 = ((k) & 2) ? arr[5] : arr[4];                    \
    floatx2 _u3 = ((k) & 2) ? arr[7] : arr[6];                    \
    floatx2 _v0 = ((k) & 4) ? _u1 : _u0;                          \
    floatx2 _v1 = ((k) & 4) ? _u3 : _u2;                          \
    floatx2 _w  = ((k) & 8) ? _v1 : _v0;                          \
    out = ((k) & 1) ? _w.y : _w.x;                                \
} while (0)

// ---------------- Kernel 0: weight transpose + f16 convert ----------------
__global__ __launch_bounds__(64) void wt_kernel(const float* __restrict__ W1,
                                                const float* __restrict__ W2,
                                                const float* __restrict__ W3,
                                                _Float16* __restrict__ wt)
{
    const int j = blockIdx.x;
    const int t = threadIdx.x;
    if (j < 64) {
        for (int k = t; k < K1P; k += 64) {
            float v = 0.f;
            if (k < 64)       v = W1[(3 + k) * 64 + j];
            else if (k < 67)  v = W1[(k - 64) * 64 + j];
            wt[j * K1P + k] = (_Float16)v;
        }
    } else if (j < 128) {
        const int r = j - 64;
        for (int k = t; k < K2P; k += 64) {
            float v = (k < 64) ? W2[k * 64 + r] : 0.f;
            wt[6656 + r * K2P + k] = (_Float16)v;
        }
    } else {
        const int r = j - 128;
        for (int k = t; k < K2P; k += 64) {
            float v = (k < 64) ? W3[k * 128 + r] : 0.f;
            wt[11264 + r * K2P + k] = (_Float16)v;
        }
    }
}

// ---------------- Fused kernel: fps producers + ballq/mlp consumers ----------
// Grid = 256 blocks x 512 threads; all blocks co-resident (1/CU) => spin-wait
// deadlock-free. Blocks 0..7: fps with FOUR update waves (256 thr x 16 pts,
// bit-exact R6 arithmetic) — waves 4..7 only match the one barrier per step.
// R17 (this round): winner COORDS ride the key exchange. The winning lane wl
// writes key + its candidate xyz (cbuf, parity double-buffered like kbuf);
// every lane pre-selects its own candidate coords via a literal-index cndmask
// tree that hides under the DPP reduce's dependency stalls. Post-barrier,
// keys AND all 4 coord records are read in parallel (one LDS latency), and
// the winner's coords are picked with cndmask reusing the key-tree compares.
// This deletes the serial sp[last] broadcast read (~130 cy/step) and the
// readlane(bi, wl). Values are bit-identical to sp reads => FPS bit-exact.
// R16 keeps: packed float2 dist state (v_pk_*_f32), top-of-window token
// flush. R15 lesson: per-step s_barrier is cheaper than any LDS polling.
// Blocks 8..255: consumers — token spin, single-wave ballq, MFMA mlp; they
// also write new_xyz from pos[token] (bit-identical to producer's sp rows).
__global__ __launch_bounds__(512, 2) void fused_kernel(
        const float* __restrict__ x, const float* __restrict__ pos,
        const float* __restrict__ b1v, const float* __restrict__ b2v,
        const float* __restrict__ b3v,
        const _Float16* __restrict__ wt,
        float* __restrict__ new_xyz, float* __restrict__ out, int* widx)
{
    __shared__ alignas(16) char smem[65792];
    const int tid  = threadIdx.x;
    const int lane = tid & 63;
    const int wv   = tid >> 6;

    if (blockIdx.x < NB) {
        // ================= FPS (4 update waves, R10 publish) =================
#pragma clang fp contract(off)
        const int b = blockIdx.x;
        float4* sp = (float4*)smem;                               // 64 KB
        unsigned long long* kbuf = (unsigned long long*)(smem + 65536); // [2][8]
        float4* cbuf = (float4*)(smem + 65664);                   // [2][4]

        const float* p = pos + (size_t)b * NP * 3;
        for (int i = tid; i < NP; i += 512) {
            sp[i] = make_float4(p[i * 3 + 0], p[i * 3 + 1], p[i * 3 + 2], 0.0f);
        }
        __syncthreads();

        if (wv >= 4) {
            // barrier companions: one arrival per step, nothing else
            for (int s = 1; s < NS; ++s) __syncthreads();
            return;
        }

        // packed coordinate state: 8 float2 pairs = 16 points per lane
        floatx2 px[8], py[8], pz[8], md[8];
#pragma unroll
        for (int j = 0; j < 8; ++j) {
            float4 v0 = sp[tid * PPT2 + 2 * j];
            float4 v1 = sp[tid * PPT2 + 2 * j + 1];
            px[j] = floatx2{v0.x, v1.x};
            py[j] = floatx2{v0.y, v1.y};
            pz[j] = floatx2{v0.z, v1.z};
            md[j] = floatx2{1e10f, 1e10f};
        }

        // current winner coords live in registers; seed with point 0 (s=0)
        float lwx, lwy, lwz;
        {
            float4 l0 = sp[0];
            lwx = l0.x; lwy = l0.y; lwz = l0.z;
        }

        int last = 0;
        if (tid == 0) {   // s=0 token
            __hip_atomic_store(widx + b * NS, 0, __ATOMIC_RELAXED,
                               __HIP_MEMORY_SCOPE_AGENT);
        }
        int tok = 0;      // per-lane latched token (wave 0 lanes 0..15 flush)

        int par = 0;
        for (int s = 1; s < NS; ++s) {
            // top-flush: tokens of steps [s-16, s-1]; the store drains to L2
            // under the dist loop, not at the barrier's vmcnt(0) drain.
            if ((s & 15) == 0 && wv == 0 && lane < 16) {
                __hip_atomic_store(widx + b * NS + (s - 16) + lane, tok,
                                   __ATOMIC_RELAXED, __HIP_MEMORY_SCOPE_AGENT);
            }

            const floatx2 lx2 = {lwx, lwx};
            const floatx2 ly2 = {lwy, lwy};
            const floatx2 lz2 = {lwz, lwz};

            float bv = 0.0f;
            int   bk = 0;                    // local candidate slot 0..15
#pragma unroll
            for (int j = 0; j < 8; ++j) {
                floatx2 dx = px[j] - lx2;            // v_pk_add_f32 (neg)
                floatx2 dy = py[j] - ly2;
                floatx2 dz = pz[j] - lz2;
                floatx2 sx = dx * dx;                // v_pk_mul_f32
                floatx2 sy = dy * dy;
                floatx2 sz = dz * dz;
                floatx2 d2 = (sx + sy) + sz;         // contract(off): exact
                float m0 = (md[j].x < d2.x) ? md[j].x : d2.x;   // jnp.minimum
                float m1 = (md[j].y < d2.y) ? md[j].y : d2.y;
                md[j].x = m0; md[j].y = m1;
                if (m0 > bv) { bv = m0; bk = 2 * j; }
                if (m1 > bv) { bv = m1; bk = 2 * j + 1; }
            }

            // own-candidate coord select: independent of the DPP chain below;
            // the scheduler interleaves it into the reduce's dependency stalls.
            float cx, cy, cz;
            SEL16(px, bk, cx);
            SEL16(py, bk, cy);
            SEL16(pz, bk, cz);

            float r = bv;
            r = fmaxf(r, dpp_mov_f32<0x111>(r));   // row_shr:1
            r = fmaxf(r, dpp_mov_f32<0x112>(r));   // row_shr:2
            r = fmaxf(r, dpp_mov_f32<0x114>(r));   // row_shr:4
            r = fmaxf(r, dpp_mov_f32<0x118>(r));   // row_shr:8
            r = fmaxf(r, dpp_mov_f32<0x142>(r));   // row_bcast:15
            r = fmaxf(r, dpp_mov_f32<0x143>(r));   // row_bcast:31
            const float gmax = __int_as_float(
                __builtin_amdgcn_readlane(__float_as_int(r), 63));

            unsigned long long mk = __ballot(bv == gmax);
            int wl = (int)__builtin_ctzll(mk);

            if (lane == wl) {
                // winning lane publishes its own key AND coords (no readlane)
                int bw = tid * PPT2 + bk;
                kbuf[par * 8 + wv] =
                    ((unsigned long long)__float_as_uint(bv) << 32) |
                    (unsigned long long)(~(unsigned)bw);
                cbuf[par * 4 + wv] = make_float4(cx, cy, cz, 0.0f);
            }
            __syncthreads();

            // parallel read: 4 keys (2 b128) + 4 coord records (4 b128) — one
            // LDS latency; then winner pick in registers.
            const ulonglong2* wb = (const ulonglong2*)(kbuf + par * 8);
            ulonglong2 q0 = wb[0], q1 = wb[1];
            float4 c0 = cbuf[par * 4 + 0];
            float4 c1 = cbuf[par * 4 + 1];
            float4 c2 = cbuf[par * 4 + 2];
            float4 c3 = cbuf[par * 4 + 3];

            bool s01 = q0.y > q0.x;
            bool s23 = q1.y > q1.x;
            unsigned long long a0 = s01 ? q0.y : q0.x;
            unsigned long long a1 = s23 ? q1.y : q1.x;
            bool sf = a1 > a0;
            unsigned long long g = sf ? a1 : a0;
            last = (int)(~(unsigned)g);

            float w01x = s01 ? c1.x : c0.x, w01y = s01 ? c1.y : c0.y, w01z = s01 ? c1.z : c0.z;
            float w23x = s23 ? c3.x : c2.x, w23y = s23 ? c3.y : c2.y, w23z = s23 ? c3.z : c2.z;
            lwx = sf ? w23x : w01x;
            lwy = sf ? w23y : w01y;
            lwz = sf ? w23z : w01z;

            // latch token in the matching lane (all threads know `last`)
            if ((s & 15) == lane) tok = last;
            par ^= 1;
        }
        // final flush: tokens of steps [1008, 1023]
        if (wv == 0 && lane < 16) {
            __hip_atomic_store(widx + b * NS + (NS - 16) + lane, tok,
                               __ATOMIC_RELAXED, __HIP_MEMORY_SCOPE_AGENT);
        }
        return;
    }

    // ================= Consumer: ballq + gather + MLP + pool =================
    const int ci = blockIdx.x - NB;   // 0..247
    const int b  = ci & 7;
    const int r0 = ci >> 3;           // 0..30

    _Float16* G   = (_Float16*)smem;            // 64*K1P halves = 13312 B
    _Float16* H1  = (_Float16*)(smem + 13312);  // 64*K2P = 9216 B
    _Float16* H2  = (_Float16*)(smem + 22528);  // 9216 B
    float*    CW  = (float*)(smem + 31744);     // 4*NCO = 2048 B
    float*    Lb  = (float*)(smem + 33792);     // 128 floats = 512 B
    short*  nbr_s = (short*)(smem + 34304);     // 128 B
    float*    qv  = (float*)(smem + 34432);     // 12 B

    const int qd = lane >> 4;         // quad
    const int c  = lane & 15;         // col within MFMA tile
    const int myrow = wv * 16 + c;    // neighbor row (waves 0-3 only)

    // weight frag hoist + bias staging (waves 0-3)
    half8v a1[3][4], a2[2][4], a3[2][8];
    float b3r = 0.f;
    if (tid < 256) {
#pragma unroll
        for (int ks = 0; ks < 3; ++ks)
#pragma unroll
            for (int mt = 0; mt < 4; ++mt)
                a1[ks][mt] = *(const half8v*)&wt[(mt * 16 + c) * K1P + ks * 32 + qd * 8];
#pragma unroll
        for (int ks = 0; ks < 2; ++ks)
#pragma unroll
            for (int mt = 0; mt < 4; ++mt)
                a2[ks][mt] = *(const half8v*)&wt[6656 + (mt * 16 + c) * K2P + ks * 32 + qd * 8];
#pragma unroll
        for (int ks = 0; ks < 2; ++ks)
#pragma unroll
            for (int mt = 0; mt < 8; ++mt)
                a3[ks][mt] = *(const half8v*)&wt[11264 + (mt * 16 + c) * K2P + ks * 32 + qd * 8];
        if (tid < 64) { Lb[tid] = b1v[tid]; Lb[64 + tid] = b2v[tid]; }
        if (tid < NCO) b3r = b3v[tid];
        half8v z = {};
        for (int i = tid; i < (64 * K1P) / 8; i += 256) ((half8v*)G)[i] = z;
    }

    for (int s = r0; s < NS; s += 31) {
        const int bs = b * NS + s;

        // ---- spin on the self-describing token (poison 0xAA.. < 0) ----
        int idx = -1, guard = 0;
        for (;;) {
            idx = __hip_atomic_load(widx + bs, __ATOMIC_RELAXED,
                                    __HIP_MEMORY_SCOPE_AGENT);
            if (idx >= 0) break;
            __builtin_amdgcn_s_sleep(8);
            if (++guard > (1 << 26)) break;   // escape hatch: fail loud, not hang
        }
        const int qidx = (idx >= 0 && idx < NP) ? idx : 0;

        // ---- wave 0: ball query into LDS (query coords from pos[qidx]);
        //      also writes this query's new_xyz (bit-identical to producer's) --
        if (wv == 0) {
#pragma clang fp contract(off)
            const float* p = pos + (size_t)b * NP * 3;
            const float qx = p[qidx * 3 + 0];
            const float qy = p[qidx * 3 + 1];
            const float qz = p[qidx * 3 + 2];
            if (lane == 0) {
                qv[0] = qx; qv[1] = qy; qv[2] = qz;
                float* o = new_xyz + (size_t)bs * 3;
                o[0] = qx; o[1] = qy; o[2] = qz;
            }
            int cnt = 0;
            for (int n0 = 0; n0 < NP; n0 += 64) {
                const int n = n0 + lane;
                float dx = qx - p[n * 3 + 0];
                float dy = qy - p[n * 3 + 1];
                float dz = qz - p[n * 3 + 2];
                float d2 = dx * dx + dy * dy + dz * dz;   // contract(off)
                bool within = d2 < 0.04f;                 // r^2, strict <
                unsigned long long m = __ballot(within);
                if (within) {
                    int slot = cnt + __popcll(m & ((1ull << lane) - 1ull));
                    if (slot < NK) nbr_s[slot] = (short)n;
                }
                cnt += (int)__popcll(m);
                if (cnt >= NK) break;
            }
            if (cnt < NK) {
                if (lane < NK - cnt) nbr_s[cnt + lane] = (short)-1;
            }
        }
        __syncthreads();   // nbr_s, qv ready

        // ---- gather (waves 0-3): thread -> neighbor tid>>2, channel quarter ----
        if (tid < 256) {
            const int ni = tid >> 2;
            const int p4 = tid & 3;
            const int n  = (int)nbr_s[ni];
            const int nn = (n < 0) ? (NP - 1) : n;    // ref: points[-1] padding
            const float* xr = x + ((size_t)b * NP + nn) * ND + p4 * 16;
#pragma unroll
            for (int i = 0; i < 4; ++i) {
                float4 v = *(const float4*)(xr + 4 * i);
                half4v h;
                h[0] = (_Float16)v.x; h[1] = (_Float16)v.y;
                h[2] = (_Float16)v.z; h[3] = (_Float16)v.w;
                *(half4v*)&G[ni * K1P + p4 * 16 + 4 * i] = h;
            }
            if (p4 == 0) {
                const float* pr = pos + (size_t)(b * NP + nn) * 3;
                float gx = pr[0] - qv[0];
                float gy = pr[1] - qv[1];
                float gz = pr[2] - qv[2];
                half2v h2; h2[0] = (_Float16)gx; h2[1] = (_Float16)gy;
                *(half2v*)&G[ni * K1P + 64] = h2;
                G[ni * K1P + 66] = (_Float16)gz;
            }
        }
        __syncthreads();

        if (tid < 256) {
            // ---- layer 1: K=96 (3 steps), out 64 ch ----
            {
                floatx4 acc[4] = {};
#pragma unroll
                for (int ks = 0; ks < 3; ++ks) {
                    half8v bf = *(const half8v*)&G[myrow * K1P + ks * 32 + qd * 8];
#pragma unroll
                    for (int mt = 0; mt < 4; ++mt)
                        acc[mt] = __builtin_amdgcn_mfma_f32_16x16x32_f16(a1[ks][mt], bf, acc[mt], 0, 0, 0);
                }
#pragma unroll
                for (int mt = 0; mt < 4; ++mt) {
                    float4 bb = *(const float4*)&Lb[mt * 16 + qd * 4];
                    half4v h;
                    h[0] = (_Float16)fmaxf(acc[mt][0] + bb.x, 0.f);
                    h[1] = (_Float16)fmaxf(acc[mt][1] + bb.y, 0.f);
                    h[2] = (_Float16)fmaxf(acc[mt][2] + bb.z, 0.f);
                    h[3] = (_Float16)fmaxf(acc[mt][3] + bb.w, 0.f);
                    *(half4v*)&H1[myrow * K2P + mt * 16 + qd * 4] = h;
                }
            }
            // ---- layer 2: K=64 (2 steps), out 64 ch ----
            {
                floatx4 acc[4] = {};
#pragma unroll
                for (int ks = 0; ks < 2; ++ks) {
                    half8v bf = *(const half8v*)&H1[myrow * K2P + ks * 32 + qd * 8];
#pragma unroll
                    for (int mt = 0; mt < 4; ++mt)
                        acc[mt] = __builtin_amdgcn_mfma_f32_16x16x32_f16(a2[ks][mt], bf, acc[mt], 0, 0, 0);
                }
#pragma unroll
                for (int mt = 0; mt < 4; ++mt) {
                    float4 bb = *(const float4*)&Lb[64 + mt * 16 + qd * 4];
                    half4v h;
                    h[0] = (_Float16)fmaxf(acc[mt][0] + bb.x, 0.f);
                    h[1] = (_Float16)fmaxf(acc[mt][1] + bb.y, 0.f);
                    h[2] = (_Float16)fmaxf(acc[mt][2] + bb.z, 0.f);
                    h[3] = (_Float16)fmaxf(acc[mt][3] + bb.w, 0.f);
                    *(half4v*)&H2[myrow * K2P + mt * 16 + qd * 4] = h;
                }
            }
            // ---- layer 3 (swapped operands): C rows = neighbors ----
            {
                floatx4 acc3[8] = {};
#pragma unroll
                for (int ks = 0; ks < 2; ++ks) {
                    half8v av = *(const half8v*)&H2[myrow * K2P + ks * 32 + qd * 8];
#pragma unroll
                    for (int mt = 0; mt < 8; ++mt)
                        acc3[mt] = __builtin_amdgcn_mfma_f32_16x16x32_f16(av, a3[ks][mt], acc3[mt], 0, 0, 0);
                }
                const short* np4 = &nbr_s[wv * 16 + qd * 4];
                const bool v0 = np4[0] >= 0, v1 = np4[1] >= 0;
                const bool v2 = np4[2] >= 0, v3 = np4[3] >= 0;
#pragma unroll
                for (int mt = 0; mt < 8; ++mt) {
                    float m = v0 ? acc3[mt][0] : -INFINITY;
                    m = fmaxf(m, v1 ? acc3[mt][1] : -INFINITY);
                    m = fmaxf(m, v2 ? acc3[mt][2] : -INFINITY);
                    m = fmaxf(m, v3 ? acc3[mt][3] : -INFINITY);
                    m = fmaxf(m, __shfl_xor(m, 16));
                    m = fmaxf(m, __shfl_xor(m, 32));
                    if (qd == 0) CW[wv * NCO + mt * 16 + c] = m;
                }
            }
        }
        __syncthreads();

        if (tid < NCO) {
            float m = fmaxf(fmaxf(CW[tid], CW[NCO + tid]),
                            fmaxf(CW[2 * NCO + tid], CW[3 * NCO + tid]));
            m += b3r;                                  // exact: add after max
            if (nbr_s[NK - 1] < 0) m = fmaxf(m, 0.f);  // ref's masked zeros
            out[(size_t)bs * NCO + tid] = m;
        }
        __syncthreads();   // protect nbr_s/G/CW before next query's ballq/gather
    }
}

extern "C" void kernel_launch(void* const* d_in, const int* in_sizes, int n_in,
                              void* d_out, int out_size, void* d_ws, size_t ws_size,
                              hipStream_t stream) {
    const float* x   = (const float*)d_in[0];
    const float* pos = (const float*)d_in[1];
    const float* W1  = (const float*)d_in[2];
    const float* b1  = (const float*)d_in[3];
    const float* W2  = (const float*)d_in[4];
    const float* b2  = (const float*)d_in[5];
    const float* W3  = (const float*)d_in[6];
    const float* b3  = (const float*)d_in[7];

    float* out0 = (float*)d_out;                        // [B,S,128]
    float* nxyz = out0 + (size_t)NB * NS * NCO;         // [B,S,3]
    int*      widxp = (int*)((char*)d_ws + WS_WIDX);    // tokens (0xAA poison < 0)
    _Float16* wtp   = (_Float16*)((char*)d_ws + WS_WT); // f16 weights, 40 KB

    wt_kernel<<<256, 64, 0, stream>>>(W1, W2, W3, wtp);
    fused_kernel<<<256, 512, 0, stream>>>(x, pos, b1, b2, b3, wtp,
                                          nxyz, out0, widxp);
}

// Round 5
// 735.090 us; speedup vs baseline: 1.2264x; 1.2264x over previous
//
#include <hip/hip_runtime.h>
#include <stdint.h>

#define NB 8
#define NP 4096
#define NS 1024
#define NK 64
#define ND 64
#define NH 64
#define NCO 128

#define PPT2 16            // producer: 4 waves x 256 threads x 16 points

// padded K strides (in halves) for conflict-free b128 LDS access
#define K1P 104            // layer1 K: 64 x-ch + 3 xyz + zeros to 96, padded to 104
#define K2P 72             // layer2/3 K: 64, padded to 72

// workspace layout (bytes)
#define WS_WIDX 0          // int[NB*NS] per-step winner index tokens (32 KB)
#define WS_WT   32768      // _Float16 weights (20480 halves = 40 KB)

typedef _Float16 half8v __attribute__((ext_vector_type(8)));
typedef _Float16 half4v __attribute__((ext_vector_type(4)));
typedef _Float16 half2v __attribute__((ext_vector_type(2)));
typedef float    floatx4 __attribute__((ext_vector_type(4)));
typedef float    floatx2 __attribute__((ext_vector_type(2)));

// DPP move helper (ctrl must be compile-time constant)
template <int CTRL>
__device__ __forceinline__ float dpp_mov_f32(float x) {
    return __int_as_float(__builtin_amdgcn_update_dpp(
        0, __float_as_int(x), CTRL, 0xf, 0xf, true));
}

// ---------------- Kernel 0: weight transpose + f16 convert ----------------
__global__ __launch_bounds__(64) void wt_kernel(const float* __restrict__ W1,
                                                const float* __restrict__ W2,
                                                const float* __restrict__ W3,
                                                _Float16* __restrict__ wt)
{
    const int j = blockIdx.x;
    const int t = threadIdx.x;
    if (j < 64) {
        for (int k = t; k < K1P; k += 64) {
            float v = 0.f;
            if (k < 64)       v = W1[(3 + k) * 64 + j];
            else if (k < 67)  v = W1[(k - 64) * 64 + j];
            wt[j * K1P + k] = (_Float16)v;
        }
    } else if (j < 128) {
        const int r = j - 64;
        for (int k = t; k < K2P; k += 64) {
            float v = (k < 64) ? W2[k * 64 + r] : 0.f;
            wt[6656 + r * K2P + k] = (_Float16)v;
        }
    } else {
        const int r = j - 128;
        for (int k = t; k < K2P; k += 64) {
            float v = (k < 64) ? W3[k * 128 + r] : 0.f;
            wt[11264 + r * K2P + k] = (_Float16)v;
        }
    }
}

// ---------------- Fused kernel: fps producers + ballq/mlp consumers ----------
// Grid = 256 blocks x 512 threads; all blocks co-resident (1/CU) => spin-wait
// deadlock-free. Blocks 0..7: fps with FOUR update waves (256 thr x 16 pts,
// bit-exact R6 arithmetic) — waves 4..7 match the one barrier per step.
// R18 (this round): REVERTED R17's coords-in-exchange (+167us: SEL16 issue
// cost in every lane > the LDS trip it saved; exchange LDS trips are
// conserved — stop attacking them). On top of R16:
//   (a) token duty (latch + 16-wide flush) moved to companion wave 4, which
//       has ~1400cy of barrier slack per step: it re-runs the 3-compare key
//       tree on the same kbuf data (bit-identical tokens) and its global
//       stores/drains hide in the slack. Update waves 0-3 now have ZERO
//       global stores in the loop => their barriers never drain vmcnt.
//   (b) sp[last] read rotated to loop bottom (issues right after the tree).
// R16 keeps: packed float2 dist state (v_pk_*_f32). R15 lesson: per-step
// s_barrier is cheaper than any LDS polling handshake.
// Blocks 8..255: consumers — token spin, single-wave ballq, MFMA mlp; they
// also write new_xyz from pos[token] (bit-identical to producer's sp rows).
__global__ __launch_bounds__(512, 2) void fused_kernel(
        const float* __restrict__ x, const float* __restrict__ pos,
        const float* __restrict__ b1v, const float* __restrict__ b2v,
        const float* __restrict__ b3v,
        const _Float16* __restrict__ wt,
        float* __restrict__ new_xyz, float* __restrict__ out, int* widx)
{
    __shared__ alignas(16) char smem[65664];
    const int tid  = threadIdx.x;
    const int lane = tid & 63;
    const int wv   = tid >> 6;

    if (blockIdx.x < NB) {
        // ================= FPS (4 update waves + wave-4 token duty) ==========
#pragma clang fp contract(off)
        const int b = blockIdx.x;
        float4* sp = (float4*)smem;                               // 64 KB
        unsigned long long* kbuf = (unsigned long long*)(smem + 65536); // [2][8]

        const float* p = pos + (size_t)b * NP * 3;
        for (int i = tid; i < NP; i += 512) {
            sp[i] = make_float4(p[i * 3 + 0], p[i * 3 + 1], p[i * 3 + 2], 0.0f);
        }
        __syncthreads();

        if (wv >= 4) {
            if (wv == 4) {
                // token duty: same barrier cadence; tree + latch + flush all
                // hidden in this wave's barrier slack. Reads kbuf[par] right
                // after barrier s; that slot is rewritten only after barrier
                // s+2 => race-free.
                int par = 0, tok = 0;   // lane0 tok init 0 == step-0 token
                for (int s = 1; s < NS; ++s) {
                    __syncthreads();
                    const ulonglong2* wb = (const ulonglong2*)(kbuf + par * 8);
                    ulonglong2 q0 = wb[0], q1 = wb[1];
                    unsigned long long a0 = (q0.y > q0.x) ? q0.y : q0.x;
                    unsigned long long a1 = (q1.y > q1.x) ? q1.y : q1.x;
                    unsigned long long g  = (a1 > a0) ? a1 : a0;
                    int last = (int)(~(unsigned)g);
                    if ((s & 15) == lane) tok = last;
                    if ((s & 15) == 15 && lane < 16) {
                        __hip_atomic_store(widx + b * NS + (s - 15) + lane, tok,
                                           __ATOMIC_RELAXED,
                                           __HIP_MEMORY_SCOPE_AGENT);
                    }
                    par ^= 1;
                }
            } else {
                // pure barrier companions: one arrival per step
                for (int s = 1; s < NS; ++s) __syncthreads();
            }
            return;
        }

        // packed coordinate state: 8 float2 pairs = 16 points per lane
        floatx2 px[8], py[8], pz[8], md[8];
#pragma unroll
        for (int j = 0; j < 8; ++j) {
            float4 v0 = sp[tid * PPT2 + 2 * j];
            float4 v1 = sp[tid * PPT2 + 2 * j + 1];
            px[j] = floatx2{v0.x, v1.x};
            py[j] = floatx2{v0.y, v1.y};
            pz[j] = floatx2{v0.z, v1.z};
            md[j] = floatx2{1e10f, 1e10f};
        }

        float4 lp = sp[0];   // step-0 winner coords (rotation prologue)
        if (tid == 0) {      // s=0 token
            __hip_atomic_store(widx + b * NS, 0, __ATOMIC_RELAXED,
                               __HIP_MEMORY_SCOPE_AGENT);
        }

        int par = 0;
        for (int s = 1; s < NS; ++s) {
            const floatx2 lx2 = {lp.x, lp.x};
            const floatx2 ly2 = {lp.y, lp.y};
            const floatx2 lz2 = {lp.z, lp.z};

            float bv = 0.0f;
            int   bi = tid * PPT2;
#pragma unroll
            for (int j = 0; j < 8; ++j) {
                floatx2 dx = px[j] - lx2;            // v_pk_add_f32 (neg)
                floatx2 dy = py[j] - ly2;
                floatx2 dz = pz[j] - lz2;
                floatx2 sx = dx * dx;                // v_pk_mul_f32
                floatx2 sy = dy * dy;
                floatx2 sz = dz * dz;
                floatx2 d2 = (sx + sy) + sz;         // contract(off): exact
                float m0 = (md[j].x < d2.x) ? md[j].x : d2.x;   // jnp.minimum
                float m1 = (md[j].y < d2.y) ? md[j].y : d2.y;
                md[j].x = m0; md[j].y = m1;
                if (m0 > bv) { bv = m0; bi = tid * PPT2 + 2 * j; }
                if (m1 > bv) { bv = m1; bi = tid * PPT2 + 2 * j + 1; }
            }

            float r = bv;
            r = fmaxf(r, dpp_mov_f32<0x111>(r));   // row_shr:1
            r = fmaxf(r, dpp_mov_f32<0x112>(r));   // row_shr:2
            r = fmaxf(r, dpp_mov_f32<0x114>(r));   // row_shr:4
            r = fmaxf(r, dpp_mov_f32<0x118>(r));   // row_shr:8
            r = fmaxf(r, dpp_mov_f32<0x142>(r));   // row_bcast:15
            r = fmaxf(r, dpp_mov_f32<0x143>(r));   // row_bcast:31
            const float gmax = __int_as_float(
                __builtin_amdgcn_readlane(__float_as_int(r), 63));

            unsigned long long mk = __ballot(bv == gmax);
            int wl = (int)__builtin_ctzll(mk);
            int bw = __builtin_amdgcn_readlane(bi, wl);

            if (lane == 0) {
                kbuf[par * 8 + wv] =
                    ((unsigned long long)__float_as_uint(gmax) << 32) |
                    (unsigned long long)(~(unsigned)bw);
            }
            __syncthreads();

            // 4-key tree (2 b128 reads, 3 compares)
            const ulonglong2* wb = (const ulonglong2*)(kbuf + par * 8);
            ulonglong2 q0 = wb[0], q1 = wb[1];
            unsigned long long a0 = (q0.y > q0.x) ? q0.y : q0.x;
            unsigned long long a1 = (q1.y > q1.x) ? q1.y : q1.x;
            unsigned long long g  = (a1 > a0) ? a1 : a0;

            const int last = (int)(~(unsigned)g);
            lp = sp[last];   // issued at loop bottom, consumed next iteration
            par ^= 1;
        }
        return;
    }

    // ================= Consumer: ballq + gather + MLP + pool =================
    const int ci = blockIdx.x - NB;   // 0..247
    const int b  = ci & 7;
    const int r0 = ci >> 3;           // 0..30

    _Float16* G   = (_Float16*)smem;            // 64*K1P halves = 13312 B
    _Float16* H1  = (_Float16*)(smem + 13312);  // 64*K2P = 9216 B
    _Float16* H2  = (_Float16*)(smem + 22528);  // 9216 B
    float*    CW  = (float*)(smem + 31744);     // 4*NCO = 2048 B
    float*    Lb  = (float*)(smem + 33792);     // 128 floats = 512 B
    short*  nbr_s = (short*)(smem + 34304);     // 128 B
    float*    qv  = (float*)(smem + 34432);     // 12 B

    const int qd = lane >> 4;         // quad
    const int c  = lane & 15;         // col within MFMA tile
    const int myrow = wv * 16 + c;    // neighbor row (waves 0-3 only)

    // weight frag hoist + bias staging (waves 0-3)
    half8v a1[3][4], a2[2][4], a3[2][8];
    float b3r = 0.f;
    if (tid < 256) {
#pragma unroll
        for (int ks = 0; ks < 3; ++ks)
#pragma unroll
            for (int mt = 0; mt < 4; ++mt)
                a1[ks][mt] = *(const half8v*)&wt[(mt * 16 + c) * K1P + ks * 32 + qd * 8];
#pragma unroll
        for (int ks = 0; ks < 2; ++ks)
#pragma unroll
            for (int mt = 0; mt < 4; ++mt)
                a2[ks][mt] = *(const half8v*)&wt[6656 + (mt * 16 + c) * K2P + ks * 32 + qd * 8];
#pragma unroll
        for (int ks = 0; ks < 2; ++ks)
#pragma unroll
            for (int mt = 0; mt < 8; ++mt)
                a3[ks][mt] = *(const half8v*)&wt[11264 + (mt * 16 + c) * K2P + ks * 32 + qd * 8];
        if (tid < 64) { Lb[tid] = b1v[tid]; Lb[64 + tid] = b2v[tid]; }
        if (tid < NCO) b3r = b3v[tid];
        half8v z = {};
        for (int i = tid; i < (64 * K1P) / 8; i += 256) ((half8v*)G)[i] = z;
    }

    for (int s = r0; s < NS; s += 31) {
        const int bs = b * NS + s;

        // ---- spin on the self-describing token (poison 0xAA.. < 0) ----
        int idx = -1, guard = 0;
        for (;;) {
            idx = __hip_atomic_load(widx + bs, __ATOMIC_RELAXED,
                                    __HIP_MEMORY_SCOPE_AGENT);
            if (idx >= 0) break;
            __builtin_amdgcn_s_sleep(8);
            if (++guard > (1 << 26)) break;   // escape hatch: fail loud, not hang
        }
        const int qidx = (idx >= 0 && idx < NP) ? idx : 0;

        // ---- wave 0: ball query into LDS (query coords from pos[qidx]);
        //      also writes this query's new_xyz (bit-identical to producer's) --
        if (wv == 0) {
#pragma clang fp contract(off)
            const float* p = pos + (size_t)b * NP * 3;
            const float qx = p[qidx * 3 + 0];
            const float qy = p[qidx * 3 + 1];
            const float qz = p[qidx * 3 + 2];
            if (lane == 0) {
                qv[0] = qx; qv[1] = qy; qv[2] = qz;
                float* o = new_xyz + (size_t)bs * 3;
                o[0] = qx; o[1] = qy; o[2] = qz;
            }
            int cnt = 0;
            for (int n0 = 0; n0 < NP; n0 += 64) {
                const int n = n0 + lane;
                float dx = qx - p[n * 3 + 0];
                float dy = qy - p[n * 3 + 1];
                float dz = qz - p[n * 3 + 2];
                float d2 = dx * dx + dy * dy + dz * dz;   // contract(off)
                bool within = d2 < 0.04f;                 // r^2, strict <
                unsigned long long m = __ballot(within);
                if (within) {
                    int slot = cnt + __popcll(m & ((1ull << lane) - 1ull));
                    if (slot < NK) nbr_s[slot] = (short)n;
                }
                cnt += (int)__popcll(m);
                if (cnt >= NK) break;
            }
            if (cnt < NK) {
                if (lane < NK - cnt) nbr_s[cnt + lane] = (short)-1;
            }
        }
        __syncthreads();   // nbr_s, qv ready

        // ---- gather (waves 0-3): thread -> neighbor tid>>2, channel quarter ----
        if (tid < 256) {
            const int ni = tid >> 2;
            const int p4 = tid & 3;
            const int n  = (int)nbr_s[ni];
            const int nn = (n < 0) ? (NP - 1) : n;    // ref: points[-1] padding
            const float* xr = x + ((size_t)b * NP + nn) * ND + p4 * 16;
#pragma unroll
            for (int i = 0; i < 4; ++i) {
                float4 v = *(const float4*)(xr + 4 * i);
                half4v h;
                h[0] = (_Float16)v.x; h[1] = (_Float16)v.y;
                h[2] = (_Float16)v.z; h[3] = (_Float16)v.w;
                *(half4v*)&G[ni * K1P + p4 * 16 + 4 * i] = h;
            }
            if (p4 == 0) {
                const float* pr = pos + (size_t)(b * NP + nn) * 3;
                float gx = pr[0] - qv[0];
                float gy = pr[1] - qv[1];
                float gz = pr[2] - qv[2];
                half2v h2; h2[0] = (_Float16)gx; h2[1] = (_Float16)gy;
                *(half2v*)&G[ni * K1P + 64] = h2;
                G[ni * K1P + 66] = (_Float16)gz;
            }
        }
        __syncthreads();

        if (tid < 256) {
            // ---- layer 1: K=96 (3 steps), out 64 ch ----
            {
                floatx4 acc[4] = {};
#pragma unroll
                for (int ks = 0; ks < 3; ++ks) {
                    half8v bf = *(const half8v*)&G[myrow * K1P + ks * 32 + qd * 8];
#pragma unroll
                    for (int mt = 0; mt < 4; ++mt)
                        acc[mt] = __builtin_amdgcn_mfma_f32_16x16x32_f16(a1[ks][mt], bf, acc[mt], 0, 0, 0);
                }
#pragma unroll
                for (int mt = 0; mt < 4; ++mt) {
                    float4 bb = *(const float4*)&Lb[mt * 16 + qd * 4];
                    half4v h;
                    h[0] = (_Float16)fmaxf(acc[mt][0] + bb.x, 0.f);
                    h[1] = (_Float16)fmaxf(acc[mt][1] + bb.y, 0.f);
                    h[2] = (_Float16)fmaxf(acc[mt][2] + bb.z, 0.f);
                    h[3] = (_Float16)fmaxf(acc[mt][3] + bb.w, 0.f);
                    *(half4v*)&H1[myrow * K2P + mt * 16 + qd * 4] = h;
                }
            }
            // ---- layer 2: K=64 (2 steps), out 64 ch ----
            {
                floatx4 acc[4] = {};
#pragma unroll
                for (int ks = 0; ks < 2; ++ks) {
                    half8v bf = *(const half8v*)&H1[myrow * K2P + ks * 32 + qd * 8];
#pragma unroll
                    for (int mt = 0; mt < 4; ++mt)
                        acc[mt] = __builtin_amdgcn_mfma_f32_16x16x32_f16(a2[ks][mt], bf, acc[mt], 0, 0, 0);
                }
#pragma unroll
                for (int mt = 0; mt < 4; ++mt) {
                    float4 bb = *(const float4*)&Lb[64 + mt * 16 + qd * 4];
                    half4v h;
                    h[0] = (_Float16)fmaxf(acc[mt][0] + bb.x, 0.f);
                    h[1] = (_Float16)fmaxf(acc[mt][1] + bb.y, 0.f);
                    h[2] = (_Float16)fmaxf(acc[mt][2] + bb.z, 0.f);
                    h[3] = (_Float16)fmaxf(acc[mt][3] + bb.w, 0.f);
                    *(half4v*)&H2[myrow * K2P + mt * 16 + qd * 4] = h;
                }
            }
            // ---- layer 3 (swapped operands): C rows = neighbors ----
            {
                floatx4 acc3[8] = {};
#pragma unroll
                for (int ks = 0; ks < 2; ++ks) {
                    half8v av = *(const half8v*)&H2[myrow * K2P + ks * 32 + qd * 8];
#pragma unroll
                    for (int mt = 0; mt < 8; ++mt)
                        acc3[mt] = __builtin_amdgcn_mfma_f32_16x16x32_f16(av, a3[ks][mt], acc3[mt], 0, 0, 0);
                }
                const short* np4 = &nbr_s[wv * 16 + qd * 4];
                const bool v0 = np4[0] >= 0, v1 = np4[1] >= 0;
                const bool v2 = np4[2] >= 0, v3 = np4[3] >= 0;
#pragma unroll
                for (int mt = 0; mt < 8; ++mt) {
                    float m = v0 ? acc3[mt][0] : -INFINITY;
                    m = fmaxf(m, v1 ? acc3[mt][1] : -INFINITY);
                    m = fmaxf(m, v2 ? acc3[mt][2] : -INFINITY);
                    m = fmaxf(m, v3 ? acc3[mt][3] : -INFINITY);
                    m = fmaxf(m, __shfl_xor(m, 16));
                    m = fmaxf(m, __shfl_xor(m, 32));
                    if (qd == 0) CW[wv * NCO + mt * 16 + c] = m;
                }
            }
        }
        __syncthreads();

        if (tid < NCO) {
            float m = fmaxf(fmaxf(CW[tid], CW[NCO + tid]),
                            fmaxf(CW[2 * NCO + tid], CW[3 * NCO + tid]));
            m += b3r;                                  // exact: add after max
            if (nbr_s[NK - 1] < 0) m = fmaxf(m, 0.f);  // ref's masked zeros
            out[(size_t)bs * NCO + tid] = m;
        }
        __syncthreads();   // protect nbr_s/G/CW before next query's ballq/gather
    }
}

extern "C" void kernel_launch(void* const* d_in, const int* in_sizes, int n_in,
                              void* d_out, int out_size, void* d_ws, size_t ws_size,
                              hipStream_t stream) {
    const float* x   = (const float*)d_in[0];
    const float* pos = (const float*)d_in[1];
    const float* W1  = (const float*)d_in[2];
    const float* b1  = (const float*)d_in[3];
    const float* W2  = (const float*)d_in[4];
    const float* b2  = (const float*)d_in[5];
    const float* W3  = (const float*)d_in[6];
    const float* b3  = (const float*)d_in[7];

    float* out0 = (float*)d_out;                        // [B,S,128]
    float* nxyz = out0 + (size_t)NB * NS * NCO;         // [B,S,3]
    int*      widxp = (int*)((char*)d_ws + WS_WIDX);    // tokens (0xAA poison < 0)
    _Float16* wtp   = (_Float16*)((char*)d_ws + WS_WT); // f16 weights, 40 KB

    wt_kernel<<<256, 64, 0, stream>>>(W1, W2, W3, wtp);
    fused_kernel<<<256, 512, 0, stream>>>(x, pos, b1, b2, b3, wtp,
                                          nxyz, out0, widxp);
}

// Round 8
// 655.590 us; speedup vs baseline: 1.3751x; 1.1213x over previous
//
#include <hip/hip_runtime.h>
#include <stdint.h>

#define NB 8
#define NP 4096
#define NS 1024
#define NK 64
#define ND 64
#define NH 64
#define NCO 128

#define PPT2 16            // producer: 4 waves x 256 threads x 16 points

// padded K strides (in halves) for conflict-free b128 LDS access
#define K1P 104            // layer1 K: 64 x-ch + 3 xyz + zeros to 96, padded to 104
#define K2P 72             // layer2/3 K: 64, padded to 72

// workspace layout (bytes)
#define WS_WIDX 0          // int[NB*NS] per-step winner index tokens (32 KB)
#define WS_WT   32768      // _Float16 weights (20480 halves = 40 KB)

typedef _Float16 half8v __attribute__((ext_vector_type(8)));
typedef _Float16 half4v __attribute__((ext_vector_type(4)));
typedef _Float16 half2v __attribute__((ext_vector_type(2)));
typedef float    floatx4 __attribute__((ext_vector_type(4)));
typedef float    floatx2 __attribute__((ext_vector_type(2)));

// DPP move helper (ctrl must be compile-time constant)
template <int CTRL>
__device__ __forceinline__ float dpp_mov_f32(float x) {
    return __int_as_float(__builtin_amdgcn_update_dpp(
        0, __float_as_int(x), CTRL, 0xf, 0xf, true));
}

// ---------------- Kernel 0: weight transpose + f16 convert ----------------
__global__ __launch_bounds__(64) void wt_kernel(const float* __restrict__ W1,
                                                const float* __restrict__ W2,
                                                const float* __restrict__ W3,
                                                _Float16* __restrict__ wt)
{
    const int j = blockIdx.x;
    const int t = threadIdx.x;
    if (j < 64) {
        for (int k = t; k < K1P; k += 64) {
            float v = 0.f;
            if (k < 64)       v = W1[(3 + k) * 64 + j];
            else if (k < 67)  v = W1[(k - 64) * 64 + j];
            wt[j * K1P + k] = (_Float16)v;
        }
    } else if (j < 128) {
        const int r = j - 64;
        for (int k = t; k < K2P; k += 64) {
            float v = (k < 64) ? W2[k * 64 + r] : 0.f;
            wt[6656 + r * K2P + k] = (_Float16)v;
        }
    } else {
        const int r = j - 128;
        for (int k = t; k < K2P; k += 64) {
            float v = (k < 64) ? W3[k * 128 + r] : 0.f;
            wt[11264 + r * K2P + k] = (_Float16)v;
        }
    }
}

// ---------------- Fused kernel: fps producers + ballq/mlp consumers ----------
// Grid = 256 blocks x 512 threads; all blocks co-resident (1/CU) => spin-wait
// deadlock-free. Blocks 0..7: fps with FOUR update waves (256 thr x 16 pts,
// bit-exact R6 arithmetic) — waves 4..7 only match the one barrier per step.
// R21 (this round): R19 resubmitted with __builtin_elementwise_min/max
// replaced by plain fminf/fmaxf (same v_min/v_max minnum/maxnum semantics,
// bit-exact) — hedging against the possibility that the two consecutive
// container failures were a toolchain crash on those vector builtins rather
// than pure infra flake. Algorithm unchanged from R19:
//   (1) pure min-update dist loop (no serial argmax chain across points);
//   (2) bv via depth-4 max tree feeding the DPP reduce immediately;
//   (3) index via descending equality scan (first j with md[j]==bv) that
//       overlaps the DPP reduce — consumed only at readlane(bi, wl).
// Tie semantics preserved exactly (maxnum returns one of its inputs bitwise
// for non-NaN; first-match scan == old strict-> first-argmax) => bit-exact.
// R16 keeps: packed float2 dist state (v_pk_*_f32), top-of-window token
// flush on wave 0. R15 lesson: per-step s_barrier beats any LDS polling.
// R17 lesson: exchange LDS trips are conserved. R18 lesson: keep token duty
// on wave 0.
// Blocks 8..255: consumers — token spin, single-wave ballq, MFMA mlp; they
// also write new_xyz from pos[token] (bit-identical to producer's sp rows).
__global__ __launch_bounds__(512, 2) void fused_kernel(
        const float* __restrict__ x, const float* __restrict__ pos,
        const float* __restrict__ b1v, const float* __restrict__ b2v,
        const float* __restrict__ b3v,
        const _Float16* __restrict__ wt,
        float* __restrict__ new_xyz, float* __restrict__ out, int* widx)
{
    __shared__ alignas(16) char smem[65664];
    const int tid  = threadIdx.x;
    const int lane = tid & 63;
    const int wv   = tid >> 6;

    if (blockIdx.x < NB) {
        // ================= FPS (4 update waves, R10 publish) =================
#pragma clang fp contract(off)
        const int b = blockIdx.x;
        float4* sp = (float4*)smem;                               // 64 KB
        unsigned long long* kbuf = (unsigned long long*)(smem + 65536); // [2][8]

        const float* p = pos + (size_t)b * NP * 3;
        for (int i = tid; i < NP; i += 512) {
            sp[i] = make_float4(p[i * 3 + 0], p[i * 3 + 1], p[i * 3 + 2], 0.0f);
        }
        __syncthreads();

        if (wv >= 4) {
            // barrier companions: one arrival per step, nothing else
            for (int s = 1; s < NS; ++s) __syncthreads();
            return;
        }

        // packed coordinate state: 8 float2 pairs = 16 points per lane
        floatx2 px[8], py[8], pz[8], md[8];
#pragma unroll
        for (int j = 0; j < 8; ++j) {
            float4 v0 = sp[tid * PPT2 + 2 * j];
            float4 v1 = sp[tid * PPT2 + 2 * j + 1];
            px[j] = floatx2{v0.x, v1.x};
            py[j] = floatx2{v0.y, v1.y};
            pz[j] = floatx2{v0.z, v1.z};
            md[j] = floatx2{1e10f, 1e10f};
        }

        int last = 0;
        if (tid == 0) {   // s=0 token
            __hip_atomic_store(widx + b * NS, 0, __ATOMIC_RELAXED,
                               __HIP_MEMORY_SCOPE_AGENT);
        }
        int tok = 0;      // per-lane latched token (wave 0 lanes 0..15 flush)

        int par = 0;
        for (int s = 1; s < NS; ++s) {
            // top-flush: tokens of steps [s-16, s-1]; the store drains to L2
            // under the dist loop, not at the barrier's vmcnt(0) drain.
            // (lane 0's tok init = 0 == step-0's token, so s=16 is correct.)
            if ((s & 15) == 0 && wv == 0 && lane < 16) {
                __hip_atomic_store(widx + b * NS + (s - 16) + lane, tok,
                                   __ATOMIC_RELAXED, __HIP_MEMORY_SCOPE_AGENT);
            }

            const float4 lp = sp[last];
            const floatx2 lx2 = {lp.x, lp.x};
            const floatx2 ly2 = {lp.y, lp.y};
            const floatx2 lz2 = {lp.z, lp.z};

            // (1) pure distance + min update — no serial chain across points
#pragma unroll
            for (int j = 0; j < 8; ++j) {
                floatx2 dx = px[j] - lx2;            // v_pk_add_f32 (neg)
                floatx2 dy = py[j] - ly2;
                floatx2 dz = pz[j] - lz2;
                floatx2 sx = dx * dx;                // v_pk_mul_f32
                floatx2 sy = dy * dy;
                floatx2 sz = dz * dz;
                floatx2 d2 = (sx + sy) + sz;         // contract(off): exact
                // minnum == (md<d2)?md:d2 for non-NaN data (bit-exact)
                md[j].x = fminf(md[j].x, d2.x);
                md[j].y = fminf(md[j].y, d2.y);
            }

            // (2) value max tree (depth ~4) -> bv feeds the DPP reduce now
            float t0x = fmaxf(md[0].x, md[1].x), t0y = fmaxf(md[0].y, md[1].y);
            float t1x = fmaxf(md[2].x, md[3].x), t1y = fmaxf(md[2].y, md[3].y);
            float t2x = fmaxf(md[4].x, md[5].x), t2y = fmaxf(md[4].y, md[5].y);
            float t3x = fmaxf(md[6].x, md[7].x), t3y = fmaxf(md[6].y, md[7].y);
            float u0x = fmaxf(t0x, t1x), u0y = fmaxf(t0y, t1y);
            float u1x = fmaxf(t2x, t3x), u1y = fmaxf(t2y, t3y);
            const float bv = fmaxf(fmaxf(u0x, u1x), fmaxf(u0y, u1y));

            // (3) equality scan for the first matching slot — independent of
            // the DPP chain below; overlaps its dependency stalls. Descending
            // order => final bk = smallest matching index (old tie semantics).
            int bk = 0;
#pragma unroll
            for (int j = 7; j >= 0; --j) {
                if (md[j].y == bv) bk = 2 * j + 1;
                if (md[j].x == bv) bk = 2 * j;
            }
            const int bi = tid * PPT2 + bk;

            float r = bv;
            r = fmaxf(r, dpp_mov_f32<0x111>(r));   // row_shr:1
            r = fmaxf(r, dpp_mov_f32<0x112>(r));   // row_shr:2
            r = fmaxf(r, dpp_mov_f32<0x114>(r));   // row_shr:4
            r = fmaxf(r, dpp_mov_f32<0x118>(r));   // row_shr:8
            r = fmaxf(r, dpp_mov_f32<0x142>(r));   // row_bcast:15
            r = fmaxf(r, dpp_mov_f32<0x143>(r));   // row_bcast:31
            const float gmax = __int_as_float(
                __builtin_amdgcn_readlane(__float_as_int(r), 63));

            unsigned long long mk = __ballot(bv == gmax);
            int wl = (int)__builtin_ctzll(mk);
            int bw = __builtin_amdgcn_readlane(bi, wl);

            if (lane == 0) {
                kbuf[par * 8 + wv] =
                    ((unsigned long long)__float_as_uint(gmax) << 32) |
                    (unsigned long long)(~(unsigned)bw);
            }
            __syncthreads();

            // 4-key tree (2 b128 reads, 3 compares)
            const ulonglong2* wb = (const ulonglong2*)(kbuf + par * 8);
            ulonglong2 q0 = wb[0], q1 = wb[1];
            unsigned long long a0 = (q0.y > q0.x) ? q0.y : q0.x;
            unsigned long long a1 = (q1.y > q1.x) ? q1.y : q1.x;
            unsigned long long g  = (a1 > a0) ? a1 : a0;

            last = (int)(~(unsigned)g);

            // latch token in the matching lane (all threads know `last`)
            if ((s & 15) == lane) tok = last;
            par ^= 1;
        }
        // final flush: tokens of steps [1008, 1023]
        if (wv == 0 && lane < 16) {
            __hip_atomic_store(widx + b * NS + (NS - 16) + lane, tok,
                               __ATOMIC_RELAXED, __HIP_MEMORY_SCOPE_AGENT);
        }
        return;
    }

    // ================= Consumer: ballq + gather + MLP + pool =================
    const int ci = blockIdx.x - NB;   // 0..247
    const int b  = ci & 7;
    const int r0 = ci >> 3;           // 0..30

    _Float16* G   = (_Float16*)smem;            // 64*K1P halves = 13312 B
    _Float16* H1  = (_Float16*)(smem + 13312);  // 64*K2P = 9216 B
    _Float16* H2  = (_Float16*)(smem + 22528);  // 9216 B
    float*    CW  = (float*)(smem + 31744);     // 4*NCO = 2048 B
    float*    Lb  = (float*)(smem + 33792);     // 128 floats = 512 B
    short*  nbr_s = (short*)(smem + 34304);     // 128 B
    float*    qv  = (float*)(smem + 34432);     // 12 B

    const int qd = lane >> 4;         // quad
    const int c  = lane & 15;         // col within MFMA tile
    const int myrow = wv * 16 + c;    // neighbor row (waves 0-3 only)

    // weight frag hoist + bias staging (waves 0-3)
    half8v a1[3][4], a2[2][4], a3[2][8];
    float b3r = 0.f;
    if (tid < 256) {
#pragma unroll
        for (int ks = 0; ks < 3; ++ks)
#pragma unroll
            for (int mt = 0; mt < 4; ++mt)
                a1[ks][mt] = *(const half8v*)&wt[(mt * 16 + c) * K1P + ks * 32 + qd * 8];
#pragma unroll
        for (int ks = 0; ks < 2; ++ks)
#pragma unroll
            for (int mt = 0; mt < 4; ++mt)
                a2[ks][mt] = *(const half8v*)&wt[6656 + (mt * 16 + c) * K2P + ks * 32 + qd * 8];
#pragma unroll
        for (int ks = 0; ks < 2; ++ks)
#pragma unroll
            for (int mt = 0; mt < 8; ++mt)
                a3[ks][mt] = *(const half8v*)&wt[11264 + (mt * 16 + c) * K2P + ks * 32 + qd * 8];
        if (tid < 64) { Lb[tid] = b1v[tid]; Lb[64 + tid] = b2v[tid]; }
        if (tid < NCO) b3r = b3v[tid];
        half8v z = {};
        for (int i = tid; i < (64 * K1P) / 8; i += 256) ((half8v*)G)[i] = z;
    }

    for (int s = r0; s < NS; s += 31) {
        const int bs = b * NS + s;

        // ---- spin on the self-describing token (poison 0xAA.. < 0) ----
        int idx = -1, guard = 0;
        for (;;) {
            idx = __hip_atomic_load(widx + bs, __ATOMIC_RELAXED,
                                    __HIP_MEMORY_SCOPE_AGENT);
            if (idx >= 0) break;
            __builtin_amdgcn_s_sleep(8);
            if (++guard > (1 << 26)) break;   // escape hatch: fail loud, not hang
        }
        const int qidx = (idx >= 0 && idx < NP) ? idx : 0;

        // ---- wave 0: ball query into LDS (query coords from pos[qidx]);
        //      also writes this query's new_xyz (bit-identical to producer's) --
        if (wv == 0) {
#pragma clang fp contract(off)
            const float* p = pos + (size_t)b * NP * 3;
            const float qx = p[qidx * 3 + 0];
            const float qy = p[qidx * 3 + 1];
            const float qz = p[qidx * 3 + 2];
            if (lane == 0) {
                qv[0] = qx; qv[1] = qy; qv[2] = qz;
                float* o = new_xyz + (size_t)bs * 3;
                o[0] = qx; o[1] = qy; o[2] = qz;
            }
            int cnt = 0;
            for (int n0 = 0; n0 < NP; n0 += 64) {
                const int n = n0 + lane;
                float dx = qx - p[n * 3 + 0];
                float dy = qy - p[n * 3 + 1];
                float dz = qz - p[n * 3 + 2];
                float d2 = dx * dx + dy * dy + dz * dz;   // contract(off)
                bool within = d2 < 0.04f;                 // r^2, strict <
                unsigned long long m = __ballot(within);
                if (within) {
                    int slot = cnt + __popcll(m & ((1ull << lane) - 1ull));
                    if (slot < NK) nbr_s[slot] = (short)n;
                }
                cnt += (int)__popcll(m);
                if (cnt >= NK) break;
            }
            if (cnt < NK) {
                if (lane < NK - cnt) nbr_s[cnt + lane] = (short)-1;
            }
        }
        __syncthreads();   // nbr_s, qv ready

        // ---- gather (waves 0-3): thread -> neighbor tid>>2, channel quarter ----
        if (tid < 256) {
            const int ni = tid >> 2;
            const int p4 = tid & 3;
            const int n  = (int)nbr_s[ni];
            const int nn = (n < 0) ? (NP - 1) : n;    // ref: points[-1] padding
            const float* xr = x + ((size_t)b * NP + nn) * ND + p4 * 16;
#pragma unroll
            for (int i = 0; i < 4; ++i) {
                float4 v = *(const float4*)(xr + 4 * i);
                half4v h;
                h[0] = (_Float16)v.x; h[1] = (_Float16)v.y;
                h[2] = (_Float16)v.z; h[3] = (_Float16)v.w;
                *(half4v*)&G[ni * K1P + p4 * 16 + 4 * i] = h;
            }
            if (p4 == 0) {
                const float* pr = pos + (size_t)(b * NP + nn) * 3;
                float gx = pr[0] - qv[0];
                float gy = pr[1] - qv[1];
                float gz = pr[2] - qv[2];
                half2v h2; h2[0] = (_Float16)gx; h2[1] = (_Float16)gy;
                *(half2v*)&G[ni * K1P + 64] = h2;
                G[ni * K1P + 66] = (_Float16)gz;
            }
        }
        __syncthreads();

        if (tid < 256) {
            // ---- layer 1: K=96 (3 steps), out 64 ch ----
            {
                floatx4 acc[4] = {};
#pragma unroll
                for (int ks = 0; ks < 3; ++ks) {
                    half8v bf = *(const half8v*)&G[myrow * K1P + ks * 32 + qd * 8];
#pragma unroll
                    for (int mt = 0; mt < 4; ++mt)
                        acc[mt] = __builtin_amdgcn_mfma_f32_16x16x32_f16(a1[ks][mt], bf, acc[mt], 0, 0, 0);
                }
#pragma unroll
                for (int mt = 0; mt < 4; ++mt) {
                    float4 bb = *(const float4*)&Lb[mt * 16 + qd * 4];
                    half4v h;
                    h[0] = (_Float16)fmaxf(acc[mt][0] + bb.x, 0.f);
                    h[1] = (_Float16)fmaxf(acc[mt][1] + bb.y, 0.f);
                    h[2] = (_Float16)fmaxf(acc[mt][2] + bb.z, 0.f);
                    h[3] = (_Float16)fmaxf(acc[mt][3] + bb.w, 0.f);
                    *(half4v*)&H1[myrow * K2P + mt * 16 + qd * 4] = h;
                }
            }
            // ---- layer 2: K=64 (2 steps), out 64 ch ----
            {
                floatx4 acc[4] = {};
#pragma unroll
                for (int ks = 0; ks < 2; ++ks) {
                    half8v bf = *(const half8v*)&H1[myrow * K2P + ks * 32 + qd * 8];
#pragma unroll
                    for (int mt = 0; mt < 4; ++mt)
                        acc[mt] = __builtin_amdgcn_mfma_f32_16x16x32_f16(a2[ks][mt], bf, acc[mt], 0, 0, 0);
                }
#pragma unroll
                for (int mt = 0; mt < 4; ++mt) {
                    float4 bb = *(const float4*)&Lb[64 + mt * 16 + qd * 4];
                    half4v h;
                    h[0] = (_Float16)fmaxf(acc[mt][0] + bb.x, 0.f);
                    h[1] = (_Float16)fmaxf(acc[mt][1] + bb.y, 0.f);
                    h[2] = (_Float16)fmaxf(acc[mt][2] + bb.z, 0.f);
                    h[3] = (_Float16)fmaxf(acc[mt][3] + bb.w, 0.f);
                    *(half4v*)&H2[myrow * K2P + mt * 16 + qd * 4] = h;
                }
            }
            // ---- layer 3 (swapped operands): C rows = neighbors ----
            {
                floatx4 acc3[8] = {};
#pragma unroll
                for (int ks = 0; ks < 2; ++ks) {
                    half8v av = *(const half8v*)&H2[myrow * K2P + ks * 32 + qd * 8];
#pragma unroll
                    for (int mt = 0; mt < 8; ++mt)
                        acc3[mt] = __builtin_amdgcn_mfma_f32_16x16x32_f16(av, a3[ks][mt], acc3[mt], 0, 0, 0);
                }
                const short* np4 = &nbr_s[wv * 16 + qd * 4];
                const bool v0 = np4[0] >= 0, v1 = np4[1] >= 0;
                const bool v2 = np4[2] >= 0, v3 = np4[3] >= 0;
#pragma unroll
                for (int mt = 0; mt < 8; ++mt) {
                    float m = v0 ? acc3[mt][0] : -INFINITY;
                    m = fmaxf(m, v1 ? acc3[mt][1] : -INFINITY);
                    m = fmaxf(m, v2 ? acc3[mt][2] : -INFINITY);
                    m = fmaxf(m, v3 ? acc3[mt][3] : -INFINITY);
                    m = fmaxf(m, __shfl_xor(m, 16));
                    m = fmaxf(m, __shfl_xor(m, 32));
                    if (qd == 0) CW[wv * NCO + mt * 16 + c] = m;
                }
            }
        }
        __syncthreads();

        if (tid < NCO) {
            float m = fmaxf(fmaxf(CW[tid], CW[NCO + tid]),
                            fmaxf(CW[2 * NCO + tid], CW[3 * NCO + tid]));
            m += b3r;                                  // exact: add after max
            if (nbr_s[NK - 1] < 0) m = fmaxf(m, 0.f);  // ref's masked zeros
            out[(size_t)bs * NCO + tid] = m;
        }
        __syncthreads();   // protect nbr_s/G/CW before next query's ballq/gather
    }
}

extern "C" void kernel_launch(void* const* d_in, const int* in_sizes, int n_in,
                              void* d_out, int out_size, void* d_ws, size_t ws_size,
                              hipStream_t stream) {
    const float* x   = (const float*)d_in[0];
    const float* pos = (const float*)d_in[1];
    const float* W1  = (const float*)d_in[2];
    const float* b1  = (const float*)d_in[3];
    const float* W2  = (const float*)d_in[4];
    const float* b2  = (const float*)d_in[5];
    const float* W3  = (const float*)d_in[6];
    const float* b3  = (const float*)d_in[7];

    float* out0 = (float*)d_out;                        // [B,S,128]
    float* nxyz = out0 + (size_t)NB * NS * NCO;         // [B,S,3]
    int*      widxp = (int*)((char*)d_ws + WS_WIDX);    // tokens (0xAA poison < 0)
    _Float16* wtp   = (_Float16*)((char*)d_ws + WS_WT); // f16 weights, 40 KB

    wt_kernel<<<256, 64, 0, stream>>>(W1, W2, W3, wtp);
    fused_kernel<<<256, 512, 0, stream>>>(x, pos, b1, b2, b3, wtp,
                                          nxyz, out0, widxp);
}